// Round 1
// baseline (911.944 us; speedup 1.0000x reference)
//
#include <hip/hip_runtime.h>
#include <cstddef>

// Problem constants (from reference)
#define NB    64    // batch
#define NHQ   32    // q heads
#define NHKV  8     // kv heads
#define HD    128   // head dim
#define BS    16    // block size (S)
#define NMB   128   // max blocks per seq
#define NG    4     // q heads per kv head (HQ/HKV)
#define LMAX  2048  // BS * NMB
#define QK_SCALE 0.08838834764831845f

__global__ __launch_bounds__(256)
void paged_gqa_decode(const float* __restrict__ q,
                      const float* __restrict__ k_cache,
                      const float* __restrict__ v_cache,
                      const int*   __restrict__ block_tables,
                      const int*   __restrict__ context_lens,
                      float* __restrict__ out)
{
    const int bh   = blockIdx.x;
    const int b    = bh >> 3;     // batch index
    const int h    = bh & 7;      // kv head index
    const int tid  = threadIdx.x;
    const int team = tid >> 5;    // 0..7, 32-lane team handles one position/iter
    const int lane = tid & 31;    // lane within team -> dims [lane*4, lane*4+4)

    __shared__ float s_p[LMAX * 4];        // [pos][4 q-heads] scores -> probs (32 KB)
    __shared__ float s_acc[8][NG][HD];     // per-team partial O (16 KB)
    __shared__ int   s_bt[NMB];            // block table for this batch
    __shared__ float s_l[NG];              // softmax denominators

    const int len = context_lens[b];

    for (int i = tid; i < NMB; i += 256) s_bt[i] = block_tables[b * NMB + i];

    // q fragments: head j, elements [lane*4, lane*4+4), pre-scaled
    const float* qb = q + ((size_t)b * NHQ + (size_t)h * NG) * HD + lane * 4;
    float4 q0 = *(const float4*)(qb);
    float4 q1 = *(const float4*)(qb + HD);
    float4 q2 = *(const float4*)(qb + 2 * HD);
    float4 q3 = *(const float4*)(qb + 3 * HD);
    q0.x *= QK_SCALE; q0.y *= QK_SCALE; q0.z *= QK_SCALE; q0.w *= QK_SCALE;
    q1.x *= QK_SCALE; q1.y *= QK_SCALE; q1.z *= QK_SCALE; q1.w *= QK_SCALE;
    q2.x *= QK_SCALE; q2.y *= QK_SCALE; q2.z *= QK_SCALE; q2.w *= QK_SCALE;
    q3.x *= QK_SCALE; q3.y *= QK_SCALE; q3.z *= QK_SCALE; q3.w *= QK_SCALE;

    __syncthreads();  // s_bt ready

    const float* kbase = k_cache + (size_t)h * HD + lane * 4;
    const float* vbase = v_cache + (size_t)h * HD + lane * 4;

    auto slot_off = [&](int p) -> size_t {
        // byte-element offset of position p's KV vector (before head/lane offset)
        return (size_t)(s_bt[p >> 4] * BS + (p & 15)) * (NHKV * HD);
    };

    // ---------------- Phase 1: scores = (q*scale) . K ----------------
    auto qk_one = [&](int p, float4 k4) {
        float d0 = q0.x * k4.x + q0.y * k4.y + q0.z * k4.z + q0.w * k4.w;
        float d1 = q1.x * k4.x + q1.y * k4.y + q1.z * k4.z + q1.w * k4.w;
        float d2 = q2.x * k4.x + q2.y * k4.y + q2.z * k4.z + q2.w * k4.w;
        float d3 = q3.x * k4.x + q3.y * k4.y + q3.z * k4.z + q3.w * k4.w;
#pragma unroll
        for (int off = 16; off >= 1; off >>= 1) {
            d0 += __shfl_xor(d0, off, 32);
            d1 += __shfl_xor(d1, off, 32);
            d2 += __shfl_xor(d2, off, 32);
            d3 += __shfl_xor(d3, off, 32);
        }
        if (lane == 0) {
            float* sp = s_p + 4 * p;
            sp[0] = d0; sp[1] = d1; sp[2] = d2; sp[3] = d3;
        }
    };

    {
        int p = team;
        for (; p + 24 < len; p += 32) {
            float4 k0 = *(const float4*)(kbase + slot_off(p));
            float4 k1 = *(const float4*)(kbase + slot_off(p + 8));
            float4 k2 = *(const float4*)(kbase + slot_off(p + 16));
            float4 k3 = *(const float4*)(kbase + slot_off(p + 24));
            qk_one(p,      k0);
            qk_one(p + 8,  k1);
            qk_one(p + 16, k2);
            qk_one(p + 24, k3);
        }
        for (; p < len; p += 8) {
            float4 k0 = *(const float4*)(kbase + slot_off(p));
            qk_one(p, k0);
        }
    }
    __syncthreads();

    // ---------------- Phase 2: softmax (one wave per q-head) ----------------
    {
        const int wv = tid >> 6;   // 0..3 = q-head within group
        const int wl = tid & 63;
        float m = -INFINITY;
        for (int p = wl; p < len; p += 64) m = fmaxf(m, s_p[4 * p + wv]);
#pragma unroll
        for (int off = 32; off >= 1; off >>= 1) m = fmaxf(m, __shfl_xor(m, off, 64));
        float l = 0.0f;
        for (int p = wl; p < len; p += 64) {
            float e = __expf(s_p[4 * p + wv] - m);
            s_p[4 * p + wv] = e;
            l += e;
        }
#pragma unroll
        for (int off = 32; off >= 1; off >>= 1) l += __shfl_xor(l, off, 64);
        if (wl == 0) s_l[wv] = l;
    }
    __syncthreads();

    // ---------------- Phase 3: O = P . V ----------------
    float4 a0 = make_float4(0.f, 0.f, 0.f, 0.f);
    float4 a1 = a0, a2 = a0, a3 = a0;

    auto pv_one = [&](int p, float4 v4) {
        const float* sp = s_p + 4 * p;
        float w0 = sp[0], w1 = sp[1], w2 = sp[2], w3 = sp[3];
        a0.x += w0 * v4.x; a0.y += w0 * v4.y; a0.z += w0 * v4.z; a0.w += w0 * v4.w;
        a1.x += w1 * v4.x; a1.y += w1 * v4.y; a1.z += w1 * v4.z; a1.w += w1 * v4.w;
        a2.x += w2 * v4.x; a2.y += w2 * v4.y; a2.z += w2 * v4.z; a2.w += w2 * v4.w;
        a3.x += w3 * v4.x; a3.y += w3 * v4.y; a3.z += w3 * v4.z; a3.w += w3 * v4.w;
    };

    {
        int p = team;
        for (; p + 24 < len; p += 32) {
            float4 v0 = *(const float4*)(vbase + slot_off(p));
            float4 v1 = *(const float4*)(vbase + slot_off(p + 8));
            float4 v2 = *(const float4*)(vbase + slot_off(p + 16));
            float4 v3 = *(const float4*)(vbase + slot_off(p + 24));
            pv_one(p,      v0);
            pv_one(p + 8,  v1);
            pv_one(p + 16, v2);
            pv_one(p + 24, v3);
        }
        for (; p < len; p += 8) {
            float4 v0 = *(const float4*)(vbase + slot_off(p));
            pv_one(p, v0);
        }
    }

    // team partials -> LDS
    *(float4*)&s_acc[team][0][lane * 4] = a0;
    *(float4*)&s_acc[team][1][lane * 4] = a1;
    *(float4*)&s_acc[team][2][lane * 4] = a2;
    *(float4*)&s_acc[team][3][lane * 4] = a3;
    __syncthreads();

    // final reduce over 8 teams + divide by l + store
    if (tid < 128) {
        const int j = tid >> 5;          // q-head within group
        const int c = (tid & 31) << 2;   // dim chunk start
        float sx = 0.f, sy = 0.f, sz = 0.f, sw = 0.f;
#pragma unroll
        for (int t = 0; t < 8; ++t) {
            const float* a = &s_acc[t][j][c];
            sx += a[0]; sy += a[1]; sz += a[2]; sw += a[3];
        }
        const float inv = 1.0f / s_l[j];
        float4 o = make_float4(sx * inv, sy * inv, sz * inv, sw * inv);
        *(float4*)(out + ((size_t)b * NHQ + (size_t)h * NG + j) * HD + c) = o;
    }
}

extern "C" void kernel_launch(void* const* d_in, const int* in_sizes, int n_in,
                              void* d_out, int out_size, void* d_ws, size_t ws_size,
                              hipStream_t stream) {
    const float* q            = (const float*)d_in[0];
    const float* k_cache      = (const float*)d_in[1];
    const float* v_cache      = (const float*)d_in[2];
    const int*   block_tables = (const int*)d_in[3];
    const int*   context_lens = (const int*)d_in[4];
    float*       out          = (float*)d_out;

    paged_gqa_decode<<<dim3(NB * NHKV), dim3(256), 0, stream>>>(
        q, k_cache, v_cache, block_tables, context_lens, out);
}